// Round 10
// baseline (195.048 us; speedup 1.0000x reference)
//
#include <hip/hip_runtime.h>

// Decoder: h = relu(x @ W1 + b1); out = clamp(0.25*(h @ W2 + b2) + 0.5, 0, 1)
// B=262144, F=16, H=24, NOUT=784. Memory-bound: 822 MB fp32 output write.
//
// History:
//  R1/R3/R4: fp32 96-VGPR W2 array spills under any launch_bounds cap.
//  R2: (256,2), fp32 fma -> 208 us.
//  R6: f16 packed v_dot2_f32_f16, (256,3) -> 182.5 us = 4.6 TB/s. BEST.
//  R8: R6 + sw-pipeline + NT bundled -> 201.8 us. Pipeline's +12 v_mov/row
//      (+19% issue) explains the regression; NT never cleanly tested.
//  R9: R6 + (256,4) -> 183.9 us NEUTRAL. Occupancy ruled out as limiter.
//  This round: exact R6 + ONE change: nontemporal stores for out.
//      Theory: default stores write-allocate in L2; the 822 MB write-once
//      stream churns L2 (allocate+drain). NT streams past L2 like the
//      6.85 TB/s fill kernel. Predict 140-158 us if right.

typedef _Float16 h2_t __attribute__((ext_vector_type(2)));
typedef float    f4_t __attribute__((ext_vector_type(4)));

static __device__ __forceinline__ unsigned int pk_h2(float lo, float hi) {
    return __builtin_bit_cast(unsigned int, __builtin_amdgcn_cvt_pkrtz(lo, hi));
}

#if __has_builtin(__builtin_amdgcn_fdot2)
static __device__ __forceinline__ float fdot2u(unsigned int a, unsigned int b, float c) {
    return __builtin_amdgcn_fdot2(__builtin_bit_cast(h2_t, a),
                                  __builtin_bit_cast(h2_t, b), c, false);
}
#else
static __device__ __forceinline__ float fdot2u(unsigned int a, unsigned int b, float c) {
    const h2_t av = __builtin_bit_cast(h2_t, a);
    const h2_t bv = __builtin_bit_cast(h2_t, b);
    return fmaf((float)av.y, (float)bv.y, fmaf((float)av.x, (float)bv.x, c));
}
#endif

#define THREADS 256
#define ROWS_PER_BLOCK 256
#define F 16
#define H 24
#define KP 12               // half2 pairs along the K=24 reduction
#define NOUT 784
#define NCHUNK (NOUT / 4)   // 196 float4 column-chunks per row

__launch_bounds__(THREADS, 3)
__global__ void decoder_kernel(const float* __restrict__ x,
                               const float* __restrict__ W1,
                               const float* __restrict__ b1,
                               const float* __restrict__ W2,
                               const float* __restrict__ b2,
                               float* __restrict__ out) {
    __shared__ float w1t[H][F];                       // W1^T
    __shared__ float b1s[H];
    __shared__ unsigned int hbuf[ROWS_PER_BLOCK][KP]; // h packed half2, 12 KB

    const int tid  = threadIdx.x;
    const int row0 = blockIdx.x * ROWS_PER_BLOCK;

    // ---- stage W1^T and b1 into LDS
    for (int idx = tid; idx < F * H; idx += THREADS) {
        const int i = idx / H, j = idx % H;           // W1 is [F][H] row-major
        w1t[j][i] = W1[idx];
    }
    if (tid < H) b1s[tid] = b1[tid];

    // ---- load this thread's x row (16 floats = 4 x float4)
    float4 xv[4];
    {
        const float* xr = x + (size_t)(row0 + tid) * F;
        #pragma unroll
        for (int q = 0; q < 4; ++q)
            xv[q] = *reinterpret_cast<const float4*>(&xr[q * 4]);
    }

    __syncthreads();

    // ---- phase 1: h = relu(x @ W1 + b1); pack pairs to half2
    #pragma unroll
    for (int g = 0; g < 3; ++g) {
        float hj[8];
        #pragma unroll
        for (int jj = 0; jj < 8; ++jj) {
            const int j = g * 8 + jj;
            float acc = b1s[j];
            #pragma unroll
            for (int q = 0; q < 4; ++q) {
                const float4 wv = *reinterpret_cast<const float4*>(&w1t[j][q * 4]);
                acc = fmaf(xv[q].x, wv.x, acc);
                acc = fmaf(xv[q].y, wv.y, acc);
                acc = fmaf(xv[q].z, wv.z, acc);
                acc = fmaf(xv[q].w, wv.w, acc);
            }
            hj[jj] = fmaxf(acc, 0.0f);
        }
        uint4 p;
        p.x = pk_h2(hj[0], hj[1]);
        p.y = pk_h2(hj[2], hj[3]);
        p.z = pk_h2(hj[4], hj[5]);
        p.w = pk_h2(hj[6], hj[7]);
        *reinterpret_cast<uint4*>(&hbuf[tid][g * 4]) = p;
    }

    __syncthreads();

    // ---- phase 2: thread owns output cols [c0, c0+3] for all 256 rows.
    // W2 packed half2 (pre-scaled 0.25) in 48 u32 regs; bias folded.
    const int cc = (tid < NCHUNK) ? tid : (NCHUNK - 1);  // clamp, no branch
    const int c0 = cc * 4;

    unsigned int w2p[KP][4];
    #pragma unroll
    for (int kp = 0; kp < KP; ++kp) {
        const float4 a = *reinterpret_cast<const float4*>(&W2[(2 * kp + 0) * NOUT + c0]);
        const float4 b = *reinterpret_cast<const float4*>(&W2[(2 * kp + 1) * NOUT + c0]);
        w2p[kp][0] = pk_h2(0.25f * a.x, 0.25f * b.x);
        w2p[kp][1] = pk_h2(0.25f * a.y, 0.25f * b.y);
        w2p[kp][2] = pk_h2(0.25f * a.z, 0.25f * b.z);
        w2p[kp][3] = pk_h2(0.25f * a.w, 0.25f * b.w);
    }
    float4 b2v = *reinterpret_cast<const float4*>(&b2[c0]);
    b2v.x = fmaf(b2v.x, 0.25f, 0.5f);
    b2v.y = fmaf(b2v.y, 0.25f, 0.5f);
    b2v.z = fmaf(b2v.z, 0.25f, 0.5f);
    b2v.w = fmaf(b2v.w, 0.25f, 0.5f);

    if (tid < NCHUNK) {
        float* outp = out + (size_t)row0 * NOUT + c0;
        for (int r = 0; r < ROWS_PER_BLOCK; ++r) {
            // h row: 3 uniform-address (broadcast) b128 reads = 12 half2
            const uint4 h0 = *reinterpret_cast<const uint4*>(&hbuf[r][0]);
            const uint4 h1 = *reinterpret_cast<const uint4*>(&hbuf[r][4]);
            const uint4 h2 = *reinterpret_cast<const uint4*>(&hbuf[r][8]);
            unsigned int hw[KP];
            hw[0] = h0.x; hw[1]  = h0.y; hw[2]  = h0.z; hw[3]  = h0.w;
            hw[4] = h1.x; hw[5]  = h1.y; hw[6]  = h1.z; hw[7]  = h1.w;
            hw[8] = h2.x; hw[9]  = h2.y; hw[10] = h2.z; hw[11] = h2.w;

            float4 acc = b2v;
            #pragma unroll
            for (int kp = 0; kp < KP; ++kp) {
                acc.x = fdot2u(hw[kp], w2p[kp][0], acc.x);
                acc.y = fdot2u(hw[kp], w2p[kp][1], acc.y);
                acc.z = fdot2u(hw[kp], w2p[kp][2], acc.z);
                acc.w = fdot2u(hw[kp], w2p[kp][3], acc.w);
            }
            f4_t o;
            o.x = fminf(fmaxf(acc.x, 0.f), 1.f);
            o.y = fminf(fmaxf(acc.y, 0.f), 1.f);
            o.z = fminf(fmaxf(acc.z, 0.f), 1.f);
            o.w = fminf(fmaxf(acc.w, 0.f), 1.f);
            __builtin_nontemporal_store(o, reinterpret_cast<f4_t*>(outp));
            outp += NOUT;
        }
    }
}

extern "C" void kernel_launch(void* const* d_in, const int* in_sizes, int n_in,
                              void* d_out, int out_size, void* d_ws, size_t ws_size,
                              hipStream_t stream) {
    const float* x  = (const float*)d_in[0];
    const float* W1 = (const float*)d_in[1];
    const float* b1 = (const float*)d_in[2];
    const float* W2 = (const float*)d_in[3];
    const float* b2 = (const float*)d_in[4];
    float* out = (float*)d_out;

    const int B = in_sizes[0] / F;              // 262144
    const int grid = B / ROWS_PER_BLOCK;        // 1024
    decoder_kernel<<<grid, THREADS, 0, stream>>>(x, W1, b1, W2, b2, out);
}

// Round 11
// 184.983 us; speedup vs baseline: 1.0544x; 1.0544x over previous
//
#include <hip/hip_runtime.h>

// Decoder: h = relu(x @ W1 + b1); out = clamp(0.25*(h @ W2 + b2) + 0.5, 0, 1)
// B=262144, F=16, H=24, NOUT=784. Memory-bound: 822 MB fp32 output write.
//
// History:
//  R2:  fp32 fma, (256,2) -> 208 us.
//  R6:  f16 v_dot2, W2 strip in 48 u32 regs, (256,3) -> 182.5 us. BEST.
//  R8:  +sw-pipeline +NT bundled -> 201.8 us (regression).
//  R9:  (256,4) -> 183.9 us neutral: occupancy not the limiter.
//  R10: NT stores alone -> 195.0 us: NT harmful, reverted.
//  This round: stage W2 into LDS (f16-packed, pre-scaled 0.25) BEFORE the
//    first barrier; phase-2 register strip comes from 12 conflict-free
//    ds_read_b128 instead of 24 post-barrier global loads.
//    -> W2 HBM traffic 77->38 MB, per-generation store-idle prologue gone.

typedef _Float16 h2_t __attribute__((ext_vector_type(2)));

static __device__ __forceinline__ unsigned int pk_h2(float lo, float hi) {
    return __builtin_bit_cast(unsigned int, __builtin_amdgcn_cvt_pkrtz(lo, hi));
}

#if __has_builtin(__builtin_amdgcn_fdot2)
static __device__ __forceinline__ float fdot2u(unsigned int a, unsigned int b, float c) {
    return __builtin_amdgcn_fdot2(__builtin_bit_cast(h2_t, a),
                                  __builtin_bit_cast(h2_t, b), c, false);
}
#else
static __device__ __forceinline__ float fdot2u(unsigned int a, unsigned int b, float c) {
    const h2_t av = __builtin_bit_cast(h2_t, a);
    const h2_t bv = __builtin_bit_cast(h2_t, b);
    return fmaf((float)av.y, (float)bv.y, fmaf((float)av.x, (float)bv.x, c));
}
#endif

#define THREADS 256
#define ROWS_PER_BLOCK 256
#define F 16
#define H 24
#define KP 12               // half2 pairs along the K=24 reduction
#define NOUT 784
#define NCHUNK (NOUT / 4)   // 196 float4 column-chunks per row

__launch_bounds__(THREADS, 3)
__global__ void decoder_kernel(const float* __restrict__ x,
                               const float* __restrict__ W1,
                               const float* __restrict__ b1,
                               const float* __restrict__ W2,
                               const float* __restrict__ b2,
                               float* __restrict__ out) {
    __shared__ float w1t[H][F];                        // W1^T, 1.5 KB
    __shared__ float b1s[H];
    __shared__ unsigned int hbuf[ROWS_PER_BLOCK][KP];  // h packed half2, 12 KB
    __shared__ unsigned int w2lds[KP][NOUT];           // W2 packed half2, 37.6 KB

    const int tid  = threadIdx.x;
    const int row0 = blockIdx.x * ROWS_PER_BLOCK;

    // ---- stage W1^T and b1 into LDS
    for (int idx = tid; idx < F * H; idx += THREADS) {
        const int i = idx / H, j = idx % H;            // W1 is [F][H] row-major
        w1t[j][i] = W1[idx];
    }
    if (tid < H) b1s[tid] = b1[tid];

    // ---- load this thread's x row (16 floats = 4 x float4)
    float4 xv[4];
    {
        const float* xr = x + (size_t)(row0 + tid) * F;
        #pragma unroll
        for (int q = 0; q < 4; ++q)
            xv[q] = *reinterpret_cast<const float4*>(&xr[q * 4]);
    }

    // ---- stage W2 into LDS, packed half2 (k-pair per u32), pre-scaled 0.25.
    // 12 k-pairs x 196 float4-chunks = 2352 items, coalesced.
    for (int item = tid; item < KP * NCHUNK; item += THREADS) {
        const int kp = item / NCHUNK;
        const int c  = (item - kp * NCHUNK) * 4;
        const float4 a = *reinterpret_cast<const float4*>(&W2[(2 * kp + 0) * NOUT + c]);
        const float4 b = *reinterpret_cast<const float4*>(&W2[(2 * kp + 1) * NOUT + c]);
        uint4 p;
        p.x = pk_h2(0.25f * a.x, 0.25f * b.x);
        p.y = pk_h2(0.25f * a.y, 0.25f * b.y);
        p.z = pk_h2(0.25f * a.z, 0.25f * b.z);
        p.w = pk_h2(0.25f * a.w, 0.25f * b.w);
        *reinterpret_cast<uint4*>(&w2lds[kp][c]) = p;
    }

    // ---- b2 for this thread's columns (folded), loaded pre-barrier too
    const int cc = (tid < NCHUNK) ? tid : (NCHUNK - 1);  // clamp, no branch
    const int c0 = cc * 4;
    float4 b2v = *reinterpret_cast<const float4*>(&b2[c0]);
    b2v.x = fmaf(b2v.x, 0.25f, 0.5f);
    b2v.y = fmaf(b2v.y, 0.25f, 0.5f);
    b2v.z = fmaf(b2v.z, 0.25f, 0.5f);
    b2v.w = fmaf(b2v.w, 0.25f, 0.5f);

    __syncthreads();   // w1t, b1s, w2lds ready

    // ---- phase 1: h = relu(x @ W1 + b1); pack pairs to half2
    #pragma unroll
    for (int g = 0; g < 3; ++g) {
        float hj[8];
        #pragma unroll
        for (int jj = 0; jj < 8; ++jj) {
            const int j = g * 8 + jj;
            float acc = b1s[j];
            #pragma unroll
            for (int q = 0; q < 4; ++q) {
                const float4 wv = *reinterpret_cast<const float4*>(&w1t[j][q * 4]);
                acc = fmaf(xv[q].x, wv.x, acc);
                acc = fmaf(xv[q].y, wv.y, acc);
                acc = fmaf(xv[q].z, wv.z, acc);
                acc = fmaf(xv[q].w, wv.w, acc);
            }
            hj[jj] = fmaxf(acc, 0.0f);
        }
        uint4 p;
        p.x = pk_h2(hj[0], hj[1]);
        p.y = pk_h2(hj[2], hj[3]);
        p.z = pk_h2(hj[4], hj[5]);
        p.w = pk_h2(hj[6], hj[7]);
        *reinterpret_cast<uint4*>(&hbuf[tid][g * 4]) = p;
    }

    __syncthreads();   // hbuf ready

    // ---- phase 2: thread owns output cols [c0, c0+3] for all 256 rows.
    // Register strip from LDS: 12 conflict-free ds_read_b128 (stride 16B).
    unsigned int w2p[KP][4];
    #pragma unroll
    for (int kp = 0; kp < KP; ++kp)
        *reinterpret_cast<uint4*>(&w2p[kp][0]) =
            *reinterpret_cast<const uint4*>(&w2lds[kp][c0]);

    if (tid < NCHUNK) {
        float* outp = out + (size_t)row0 * NOUT + c0;
        for (int r = 0; r < ROWS_PER_BLOCK; ++r) {
            // h row: 3 uniform-address (broadcast) b128 reads = 12 half2
            const uint4 h0 = *reinterpret_cast<const uint4*>(&hbuf[r][0]);
            const uint4 h1 = *reinterpret_cast<const uint4*>(&hbuf[r][4]);
            const uint4 h2 = *reinterpret_cast<const uint4*>(&hbuf[r][8]);
            unsigned int hw[KP];
            hw[0] = h0.x; hw[1]  = h0.y; hw[2]  = h0.z; hw[3]  = h0.w;
            hw[4] = h1.x; hw[5]  = h1.y; hw[6]  = h1.z; hw[7]  = h1.w;
            hw[8] = h2.x; hw[9]  = h2.y; hw[10] = h2.z; hw[11] = h2.w;

            float4 acc = b2v;
            #pragma unroll
            for (int kp = 0; kp < KP; ++kp) {
                acc.x = fdot2u(hw[kp], w2p[kp][0], acc.x);
                acc.y = fdot2u(hw[kp], w2p[kp][1], acc.y);
                acc.z = fdot2u(hw[kp], w2p[kp][2], acc.z);
                acc.w = fdot2u(hw[kp], w2p[kp][3], acc.w);
            }
            float4 o;
            o.x = fminf(fmaxf(acc.x, 0.f), 1.f);
            o.y = fminf(fmaxf(acc.y, 0.f), 1.f);
            o.z = fminf(fmaxf(acc.z, 0.f), 1.f);
            o.w = fminf(fmaxf(acc.w, 0.f), 1.f);
            *reinterpret_cast<float4*>(outp) = o;
            outp += NOUT;
        }
    }
}

extern "C" void kernel_launch(void* const* d_in, const int* in_sizes, int n_in,
                              void* d_out, int out_size, void* d_ws, size_t ws_size,
                              hipStream_t stream) {
    const float* x  = (const float*)d_in[0];
    const float* W1 = (const float*)d_in[1];
    const float* b1 = (const float*)d_in[2];
    const float* W2 = (const float*)d_in[3];
    const float* b2 = (const float*)d_in[4];
    float* out = (float*)d_out;

    const int B = in_sizes[0] / F;              // 262144
    const int grid = B / ROWS_PER_BLOCK;        // 1024
    decoder_kernel<<<grid, THREADS, 0, stream>>>(x, W1, b1, W2, b2, out);
}